// Round 16
// baseline (52.824 us; speedup 1.0000x reference)
//
#include <hip/hip_runtime.h>
#include <cmath>

// Noisy 8-qubit density-matrix sim, batch 32, depth 6 — BALANCED SPLIT, single kernel.
// E_b = Tr((Λ25†(Z0) ⊗ I) · Λ01(ρ_b)):
//   backward: adjoint layers 5..2, lightcone-pruned = 10 stages, support {0..4}
//             (1024-el slab, threads 0-255, 4-way split — r11 algebra, new masks/tables)
//   forward:  layers 0..1 cone-pruned = 11 stages (T(0..5,0), T(0..4,1)) on 7-qubit
//             16384-el slab, all 1024 threads (r15 fstage verbatim).
//             T(6,0) reduced over traced q7 to a 1q map on q6 (γ7 = n1.C·sin(x7),
//             noise2(q6), R(6)) and folded into contraction weights W[r6,c6].
//             T(5,1),T(6,1) dropped (CPTP on traced qubits).
// Both chains run concurrently per block (disjoint LDS); contraction fused in-block.
// 32 blocks, ONE launch, no workspace traffic.

typedef float2 cplx;
#define BATCH 32

__device__ __forceinline__ cplx cmul(cplx a, cplx b){
  return make_float2(a.x*b.x - a.y*b.y, a.x*b.y + a.y*b.x);
}
__device__ __forceinline__ cplx cadd(cplx a, cplx b){ return make_float2(a.x+b.x, a.y+b.y); }
__device__ __forceinline__ cplx lc(float a, cplx u, float b, cplx v){
  return make_float2(a*u.x + b*v.x, a*u.y + b*v.y);
}
__device__ __forceinline__ cplx sc(float a, cplx u){ return make_float2(a*u.x, a*u.y); }

struct N1C { float A,B,C,D,E; };
__device__ __forceinline__ N1C noise_coeffs(float g){
  float ga = g*0.3f, gp = g*0.2f, p = g*0.5f;
  N1C n;
  n.A = 1.0f - 2.0f*p/3.0f;
  n.D = 2.0f*p/3.0f;
  n.B = ga*n.A + n.D*(1.0f-ga);
  n.E = n.D*ga + n.A*(1.0f-ga);
  n.C = (1.0f - 4.0f*p/3.0f) * sqrtf(1.0f-ga) * sqrtf(1.0f-gp);
  return n;
}
__device__ __forceinline__ N1C mkadj(N1C n){
  N1C a; a.A=n.A; a.B=n.D; a.C=n.C; a.D=n.B; a.E=n.E; return a;
}

__device__ __forceinline__ int ins0(int x, int p){
  int low = x & ((1<<p)-1);
  return ((x>>p)<<(p+1)) | low;
}

// backward 10-bit space (qubits 0..4: col bit 4-q, row bit 9-q); V = 4-q, V=1..4.
// free positions per V (6 g-bits), ascending:
template<int V>
__device__ __forceinline__ int baseB(int g){
  constexpr int F[5][6] = {
    {0,0,0,0,0,0},
    {2,3,4,7,8,9},   // V=1 (active {0,1,5,6})
    {0,3,4,5,8,9},   // V=2 (active {1,2,6,7})
    {0,1,4,5,6,9},   // V=3 (active {2,3,7,8})
    {0,1,2,5,6,7}};  // V=4 (active {3,4,8,9})
  int b = 0;
  #pragma unroll
  for (int i=0;i<6;i++) b ^= (-((g>>i)&1)) & (1<<F[V][i]);
  return b;
}

__device__ __forceinline__ void rot_pair(cplx& v0, cplx& v1, float cy, float sy){
  cplx a=v0, b=v1;
  v0 = make_float2(cy*a.x - sy*b.x, cy*a.y - sy*b.y);
  v1 = make_float2(sy*a.x + cy*b.x, sy*a.y + cy*b.y);
}

// ---------------- backward 4-way adjoint stage (r11 algebra, 10-bit masks) ----------------
template<int V>
__device__ __forceinline__ void astage_q4b(cplx* __restrict__ slab, float4 rc, int bp,
                                           int bsel, int dsel, N1C n1a, N1C n2a,
                                           float alpha, float beta){
  constexpr int KA=1<<(5+V), KB=1<<(4+V), KC=1<<V, KD=1<<(V-1);
  int fix = (bsel?KB:0) ^ (dsel?KD:0);
  cplx v[4];
  v[0] = slab[bp ^ fix];
  v[1] = slab[bp ^ fix ^ KC];
  v[2] = slab[bp ^ fix ^ KA];
  v[3] = slab[bp ^ fix ^ KA ^ KC];
  cplx p  = make_float2(rc.z, -rc.w);
  cplx pc = make_float2(rc.z,  rc.w);
  float cy=rc.x, sy=-rc.y;
  {
    cplx t00=v[0], t11=v[3];
    v[0]=lc(n1a.A,t00, n1a.B,t11);
    v[3]=lc(n1a.D,t00, n1a.E,t11);
    v[1]=cmul(p,v[1]); v[2]=cmul(pc,v[2]);
    rot_pair(v[0],v[1],cy,sy); rot_pair(v[2],v[3],cy,sy);
    rot_pair(v[0],v[2],cy,sy); rot_pair(v[1],v[3],cy,sy);
  }
  #pragma unroll
  for (int j=0;j<4;j++){
    float rx = __shfl_xor(v[j].x, 3, 64);
    float ry = __shfl_xor(v[j].y, 3, 64);
    v[j] = make_float2(alpha*v[j].x + beta*rx, alpha*v[j].y + beta*ry);
  }
  {
    cplx t00=v[0], t11=v[3];
    v[0]=lc(n2a.A,t00, n2a.B,t11);
    v[3]=lc(n2a.D,t00, n2a.E,t11);
    v[1]=sc(n2a.C,v[1]); v[2]=sc(n2a.C,v[2]);
  }
  int sb = bsel ? KB : 0;
  slab[bp ^ sb            ^ (dsel?KD:0)]      = v[0];
  slab[bp ^ sb ^ KC       ^ (dsel?0:KD)]      = v[1];
  slab[bp ^ (sb^KB) ^ KA  ^ (dsel?KD:0)]      = v[2];
  slab[bp ^ (sb^KB) ^ KA ^ KC ^ (dsel?0:KD)]  = v[3];
}

// ---------------- forward fused stage (r15 verbatim, cleaned), 14-bit slab ----------------
__device__ __forceinline__ void fstage(cplx* slab, const cplx* __restrict__ S, int u, int t){
  N1C n2 = noise_coeffs(0.0065f);
  int base = ins0(ins0(ins0(ins0(t, u-1), u), 6+u), 7+u);
  int ru1 = 1<<(7+u), ru0 = 1<<(6+u), cu1 = 1<<u, cu0 = 1<<(u-1);
  cplx h[16];
  #pragma unroll
  for (int idx=0; idx<16; idx++){
    int a=(idx>>3)&1, b=(idx>>2)&1, cc=(idx>>1)&1, d=idx&1;
    int pos = base + a*ru1 + (b^a)*ru0 + cc*cu1 + (d^cc)*cu0;
    h[idx] = slab[pos];
  }
  #pragma unroll
  for (int b=0;b<2;b++)
    #pragma unroll
    for (int d=0;d<2;d++){
      int i00 = (b<<2)|d;
      cplx t00=h[i00], t01=h[i00|2], t10=h[i00|8], t11=h[i00|10];
      h[i00]    = lc(n2.A,t00, n2.B,t11);
      h[i00|2]  = sc(n2.C, t01);
      h[i00|8]  = sc(n2.C, t10);
      h[i00|10] = lc(n2.D,t00, n2.E,t11);
    }
  #pragma unroll
  for (int a=0;a<2;a++)
    #pragma unroll
    for (int cc=0;cc<2;cc++){
      int i00 = (a<<3)|(cc<<1);
      cplx t00=h[i00], t01=h[i00|1], t10=h[i00|4], t11=h[i00|5];
      h[i00]   = lc(n2.A,t00, n2.B,t11);
      h[i00|1] = sc(n2.C, t01);
      h[i00|4] = sc(n2.C, t10);
      h[i00|5] = lc(n2.D,t00, n2.E,t11);
    }
  #pragma unroll
  for (int b=0;b<2;b++)
    #pragma unroll
    for (int d=0;d<2;d++){
      int i0 = (b<<2)|d;
      cplx v0=h[i0], v1=h[i0|2], v2=h[i0|8], v3=h[i0|10];
      h[i0]    = cadd(cadd(cmul(S[0],v0),  cmul(S[1],v1)),  cadd(cmul(S[2],v2),  cmul(S[3],v3)));
      h[i0|2]  = cadd(cadd(cmul(S[4],v0),  cmul(S[5],v1)),  cadd(cmul(S[6],v2),  cmul(S[7],v3)));
      h[i0|8]  = cadd(cadd(cmul(S[8],v0),  cmul(S[9],v1)),  cadd(cmul(S[10],v2), cmul(S[11],v3)));
      h[i0|10] = cadd(cadd(cmul(S[12],v0), cmul(S[13],v1)), cadd(cmul(S[14],v2), cmul(S[15],v3)));
    }
  #pragma unroll
  for (int idx=0; idx<16; idx++){
    int a=(idx>>3)&1, b=(idx>>2)&1, cc=(idx>>1)&1, d=idx&1;
    int pos = base + a*ru1 + b*ru0 + cc*cu1 + d*cu0;
    slab[pos] = h[idx];
  }
}

#define SLOT(V, SSI, S0I, UU) { \
  if (t < 256) astage_q4b<V>(bslab, sS[SSI], baseB<V>(gg), bsel, dsel, n1a, n2a, alpha, beta); \
  fstage(fslab, S0 + (S0I)*16, UU, t); \
  __syncthreads(); }

// ---------------- the whole pipeline: 32 blocks, one per sample ----------------
__global__ __launch_bounds__(1024) void fused_kernel(const float* __restrict__ x,
                                                     const float* __restrict__ w,
                                                     float* __restrict__ out){
  __shared__ cplx fslab[16384];     // 128 KB: forward 7-qubit state
  __shared__ cplx bslab[1024];      // 8 KB: backward 5-qubit operator
  __shared__ cplx S0[192];          // 12 dense superops
  __shared__ float4 sS[48];         // backward stage constants
  __shared__ float sm[28];          // encode 2x2s, qubits 0..6
  __shared__ cplx Wq[4];            // folded T(6,0) contraction weights
  __shared__ float red[16];
  int t = threadIdx.x, s = blockIdx.x;
  int dsel = t & 1, bsel = (t >> 1) & 1;
  int gg = (t >> 2) & 63;
  N1C n1a = mkadj(noise_coeffs(0.0003f));
  N1C n2a = mkadj(noise_coeffs(0.0065f));
  float alpha = (bsel==dsel) ? (bsel ? n2a.E : n2a.A) : n2a.C;
  float beta  = (bsel==dsel) ? (bsel ? n2a.D : n2a.B) : 0.f;

  // ---- prep: 12 dense superops (layer0 q0..5, layer1 q0..4, layer0 q6) ----
  if (t < 12){
    int l = (t<6) ? 0 : ((t<11) ? 1 : 0);
    int i = (t<6) ? t : ((t<11) ? (t-6) : 6);
    N1C n1 = noise_coeffs(0.0003f);
    float w0 = w[(l*8+i)*2 + 0];
    float w1 = w[(l*8+i)*2 + 1];
    float c = cosf(0.5f*w0), sn = sinf(0.5f*w0);
    float U[2][2] = {{c,-sn},{sn,c}};
    cplx ph01 = make_float2(cosf(w1), -sinf(w1));
    cplx ph10 = make_float2(ph01.x, -ph01.y);
    cplx* S = S0 + t*16;
    #pragma unroll
    for (int a=0;a<2;a++)
      #pragma unroll
      for (int b=0;b<2;b++){
        int k = 2*a+b;
        float u0a=U[0][a], u0b=U[0][b], u1a=U[1][a], u1b=U[1][b];
        S[0*4+k] = make_float2(n1.A*u0a*u0b + n1.B*u1a*u1b, 0.f);
        S[1*4+k] = sc(n1.C*u0a*u1b, ph01);
        S[2*4+k] = sc(n1.C*u1a*u0b, ph10);
        S[3*4+k] = make_float2(n1.D*u0a*u0b + n1.E*u1a*u1b, 0.f);
      }
  }
  if (t < 48){
    N1C n1 = noise_coeffs(0.0003f);
    float w0=w[t*2], w1=w[t*2+1];
    sS[t] = make_float4(cosf(0.5f*w0), sinf(0.5f*w0), n1.C*cosf(w1), -n1.C*sinf(w1));
  }
  if (t < 7){
    N1C n1 = noise_coeffs(0.0003f);
    float xv = x[s*8+t];
    float c = cosf(0.5f*xv), sn = sinf(0.5f*xv);
    float p00=c*c, p01=c*sn, p11=sn*sn;
    sm[t*4+0]=n1.A*p00+n1.B*p11; sm[t*4+1]=n1.C*p01;
    sm[t*4+2]=n1.C*p01;          sm[t*4+3]=n1.D*p00+n1.E*p11;
  }
  __syncthreads();

  // ---- W: reduced T(6,0) over traced q7, folded to contraction weights ----
  if (t == 0){
    N1C n1 = noise_coeffs(0.0003f);
    N1C n2 = noise_coeffs(0.0065f);
    float g7 = n1.C * sinf(x[s*8+7]);       // m7[01]+m7[10]
    const cplx* S = S0 + 11*16;             // dense R(6) superop (l=0, q=6)
    cplx wc0 = cadd(S[0],  S[12]);          // diag-out sums per input pair
    cplx wc1 = cadd(S[1],  S[13]);
    cplx wc2 = cadd(S[2],  S[14]);
    cplx wc3 = cadd(S[3],  S[15]);
    Wq[0] = cadd(sc(n2.A,wc0), sc(n2.D,wc3));        // in (r6,c6)=(0,0)
    Wq[1] = sc(g7*n2.C, wc1);                        // (0,1)
    Wq[2] = sc(g7*n2.C, wc2);                        // (1,0)
    Wq[3] = cadd(sc(n2.B,wc0), sc(n2.E,wc3));        // (1,1)
  }

  // ---- forward init: 7-qubit product state (q7 traced: factor 1) ----
  #pragma unroll
  for (int k=0;k<16;k++){
    int L = k*1024 + t, rl = L>>7, cl = L&127;
    float v = 1.f;
    #pragma unroll
    for (int q=0;q<7;q++)
      v *= sm[q*4 + ((rl>>(6-q))&1)*2 + ((cl>>(6-q))&1)];
    fslab[L] = make_float2(v, 0.f);
  }
  // ---- backward init: Z0 on 5-qubit space (qubit0 = bit 4 of row) ----
  if (t < 256){
    #pragma unroll
    for (int k=0;k<4;k++){
      int o = k*256 + t, r = o>>5, c = o&31;
      bslab[o] = make_float2((r==c) ? ((r&16)? -1.f : 1.f) : 0.f, 0.f);
    }
  }
  __syncthreads();

  // ---- 11 slots: forward layers 0..1; backward layers 5..2 piggyback (slots 0..9) ----
  SLOT(4, 5*8+0, 0, 6)   // bwd T+(0,5) | fwd T(0,0)
  SLOT(3, 4*8+1, 1, 5)   // bwd T+(1,4) | fwd T(1,0)
  SLOT(4, 4*8+0, 2, 4)   // bwd T+(0,4) | fwd T(2,0)
  SLOT(2, 3*8+2, 3, 3)   // bwd T+(2,3) | fwd T(3,0)
  SLOT(3, 3*8+1, 4, 2)   // bwd T+(1,3) | fwd T(4,0)
  SLOT(4, 3*8+0, 5, 1)   // bwd T+(0,3) | fwd T(5,0)
  SLOT(1, 2*8+3, 6, 6)   // bwd T+(3,2) | fwd T(0,1)
  SLOT(2, 2*8+2, 7, 5)   // bwd T+(2,2) | fwd T(1,1)
  SLOT(3, 2*8+1, 8, 4)   // bwd T+(1,2) | fwd T(2,1)
  SLOT(4, 2*8+0, 9, 3)   // bwd T+(0,2) | fwd T(3,1)
  { fstage(fslab, S0 + 10*16, 2, t); __syncthreads(); }   // fwd T(4,1)

  // ---- contraction: E = sum_o O[o] * sum_{b5,(r6,c6)} W[r6,c6] * rho[idx] ----
  float acc;
  {
    int r04 = t >> 5, c04 = t & 31;
    cplx Ov = bslab[t];
    cplx z = make_float2(0.f, 0.f);
    #pragma unroll
    for (int b5=0;b5<2;b5++)
      #pragma unroll
      for (int rc6=0;rc6<4;rc6++){
        int idx = (c04<<9) | (b5<<8) | ((rc6>>1)<<7) | (r04<<2) | (b5<<1) | (rc6&1);
        z = cadd(z, cmul(Wq[rc6], fslab[idx]));
      }
    acc = Ov.x*z.x - Ov.y*z.y;
  }
  #pragma unroll
  for (int off=32; off>0; off>>=1) acc += __shfl_down(acc, off, 64);
  if ((t&63)==0) red[t>>6] = acc;
  __syncthreads();
  if (t==0){
    float v = 0.f;
    #pragma unroll
    for (int k=0;k<16;k++) v += red[k];
    out[s] = v;
  }
}

extern "C" void kernel_launch(void* const* d_in, const int* in_sizes, int n_in,
                              void* d_out, int out_size, void* d_ws, size_t ws_size,
                              hipStream_t stream) {
  const float* x = (const float*)d_in[0];   // [32,8]
  const float* w = (const float*)d_in[1];   // [6,8,2]
  float* out = (float*)d_out;               // [32,1] f32

  fused_kernel<<<BATCH, 1024, 0, stream>>>(x, w, out);
}

// Round 17
// 22.381 us; speedup vs baseline: 2.3602x; 2.3602x over previous
//
#include <hip/hip_runtime.h>
#include <cmath>

// Noisy 8-qubit density-matrix sim, batch 32, depth 6 — split ℓ=2, BOTH chains cheap.
// E_b = Tr[(Λ25†(Z0) ⊗ I) · Λ01(ρ_b)]:
//   backward (threads 512-767): adjoint layers 5..2, lightcone = 10 stages, support {0..4},
//     1024-el bslab, r11 astage_q4 algebra with 10-bit masks + rot2 swizzle.
//   forward (threads 0-511): layers 0..1 lightcone-reduced on a 6-qubit 4096-el fslab:
//     T(0..4,0), redT(5,0) [1q on q5: dephase γ6=n1.C·sin(x6), n2, R(5)], T(0..4,1).
//     T(6,0),T(5,1),T(6,1) drop (CPTP on traced qubits — r16-verified argument).
//     2-way split (8 els/thread), target-wire noise via shfl_xor(1).
// 11 slots, wave-specialized concurrency; contraction (trace q5 = identity) fused in-block.
// 32 blocks (one per sample), ONE launch.

typedef float2 cplx;
#define BATCH 32

__device__ __forceinline__ cplx cmul(cplx a, cplx b){
  return make_float2(a.x*b.x - a.y*b.y, a.x*b.y + a.y*b.x);
}
__device__ __forceinline__ cplx lc(float a, cplx u, float b, cplx v){
  return make_float2(a*u.x + b*v.x, a*u.y + b*v.y);
}
__device__ __forceinline__ cplx sc(float a, cplx u){ return make_float2(a*u.x, a*u.y); }

struct N1C { float A,B,C,D,E; };
__device__ __forceinline__ N1C noise_coeffs(float g){
  float ga = g*0.3f, gp = g*0.2f, p = g*0.5f;
  N1C n;
  n.A = 1.0f - 2.0f*p/3.0f;
  n.D = 2.0f*p/3.0f;
  n.B = ga*n.A + n.D*(1.0f-ga);
  n.E = n.D*ga + n.A*(1.0f-ga);
  n.C = (1.0f - 4.0f*p/3.0f) * sqrtf(1.0f-ga) * sqrtf(1.0f-gp);
  return n;
}
__device__ __forceinline__ N1C mkadj(N1C n){
  N1C a; a.A=n.A; a.B=n.D; a.C=n.C; a.D=n.B; a.E=n.E; return a;
}

// ---- forward 12-bit slab: qubit q: col bit 5-q, row bit 11-q; phys = L ^ rot3(rl) ----
__device__ __forceinline__ int physof(int L){
  int rl = L >> 6;
  int rot = ((rl<<3)|(rl>>3)) & 63;
  return L ^ rot;
}
__device__ __forceinline__ constexpr int KPc(int p){
  return (p < 6) ? (1<<p) : ((1<<p) | (1 << ((p-3)%6)));
}
// ---- backward 10-bit slab: qubit q: col bit 4-q, row bit 9-q; phys = L ^ rot2(rl) ----
__device__ __forceinline__ int physB(int L){
  int rl = L >> 5;
  int rot = ((rl<<2)|(rl>>3)) & 31;
  return L ^ rot;
}
__device__ __forceinline__ constexpr int maskB(int p){
  return (p < 5) ? (1<<p) : ((1<<p) | (1 << ((p-3)%5)));
}

// forward 2-way tables: lane=(g<<1)|bsel; 8 free positions; t0..t3 bank-distinct
template<int U>
__device__ __forceinline__ int baseF(int g){
  constexpr int F[6][8] = {
    {0,0,0,0,0,0,0,0},
    {2,4,9, 3,5,8,10,11},   // U=1 (active {0,1,6,7})
    {0,3,5, 4,6,9,10,11},   // U=2 (active {1,2,7,8})
    {0,1,4, 5,6,7,10,11},   // U=3 (active {2,3,8,9})
    {1,2,5, 0,6,7,8,11},    // U=4 (active {3,4,9,10})
    {0,2,3, 1,6,7,8,9}};    // U=5 (active {4,5,10,11})
  int b = 0;
  #pragma unroll
  for (int i=0;i<8;i++) b ^= (-((g>>i)&1)) & KPc(F[U][i]);
  return b;
}
// backward 4-way tables: lane=(g<<2)|(bsel<<1)|dsel; 6 free positions
template<int V>
__device__ __forceinline__ int baseBk(int g){
  constexpr int F[5][6] = {
    {0,0,0,0,0,0},
    {3,4, 2,7,8,9},   // V=1 (active {0,1,5,6})
    {0,4, 3,5,8,9},   // V=2 (active {1,2,6,7})
    {0,1, 4,5,6,9},   // V=3 (active {2,3,7,8})
    {1,2, 0,5,6,7}};  // V=4 (active {3,4,8,9})
  int b = 0;
  #pragma unroll
  for (int i=0;i<6;i++) b ^= (-((g>>i)&1)) & maskB(F[V][i]);
  return b;
}
// free positions for the 1q q5-stage (actives {0,6}) — r9's verified base_s
__device__ __forceinline__ int base_s(int t){
  constexpr int P[10] = {1,2,3,9, 4,5,7,8,10,11};
  int b = 0;
  #pragma unroll
  for (int i=0;i<10;i++) b ^= (-((t>>i)&1)) & KPc(P[i]);
  return b;
}

__device__ __forceinline__ void rot_pair(cplx& v0, cplx& v1, float cy, float sy){
  cplx a=v0, b=v1;
  v0 = make_float2(cy*a.x - sy*b.x, cy*a.y - sy*b.y);
  v1 = make_float2(sy*a.x + cy*b.x, sy*a.y + cy*b.y);
}

// ---------------- forward 2-way stage: thread owns row-target bit b=bsel, 8 els ----------------
// h idx = (a<<2)|(cc<<1)|d ; CNOT folded in gather; tgt noise cross via shfl_xor(1).
template<int U>
__device__ __forceinline__ void fstage2(cplx* __restrict__ slab, float4 rc, int bp, int bsel,
                                        N1C n1, N1C n2, float a0, float b0, float a1, float b1){
  constexpr int KA=KPc(6+U), KB=KPc(5+U), KC=1<<U, KD=1<<(U-1);
  cplx h[8];
  #pragma unroll
  for (int i=0;i<8;i++){
    int a=(i>>2)&1, cc=(i>>1)&1, d=i&1;
    h[i] = slab[bp ^ (a?KA:0) ^ ((bsel^a)?KB:0) ^ (cc?KC:0) ^ ((d^cc)?KD:0)];
  }
  // noise2 ctl on (a,cc) per d
  #pragma unroll
  for (int d=0;d<2;d++){
    cplx t00=h[d], t11=h[6|d];
    h[d]   = lc(n2.A,t00, n2.B,t11);
    h[6|d] = lc(n2.D,t00, n2.E,t11);
    h[2|d] = sc(n2.C, h[2|d]);
    h[4|d] = sc(n2.C, h[4|d]);
  }
  // noise2 tgt cross (b,d): partner lane^1
  #pragma unroll
  for (int j=0;j<4;j++){
    int i0 = j<<1;
    float r0x = __shfl_xor(h[i0].x, 1, 64),   r0y = __shfl_xor(h[i0].y, 1, 64);
    float r1x = __shfl_xor(h[i0|1].x, 1, 64), r1y = __shfl_xor(h[i0|1].y, 1, 64);
    cplx h0 = h[i0], h1 = h[i0|1];
    h[i0]   = make_float2(a0*h0.x + b0*r1x, a0*h0.y + b0*r1y);
    h[i0|1] = make_float2(a1*h1.x + b1*r0x, a1*h1.y + b1*r0y);
  }
  // R(ctl) factored: Ycol, Yrow, then sparse N1·Drz (r5-verified order)
  float cy=rc.x, sy=rc.y;
  #pragma unroll
  for (int a=0;a<2;a++)
    #pragma unroll
    for (int d=0;d<2;d++) rot_pair(h[(a<<2)|d], h[(a<<2)|2|d], cy, sy);
  #pragma unroll
  for (int cc=0;cc<2;cc++)
    #pragma unroll
    for (int d=0;d<2;d++) rot_pair(h[(cc<<1)|d], h[4|(cc<<1)|d], cy, sy);
  cplx p = make_float2(rc.z, rc.w), pcj = make_float2(rc.z, -rc.w);
  #pragma unroll
  for (int d=0;d<2;d++){
    cplx t00=h[d], t11=h[6|d];
    h[d]   = lc(n1.A,t00, n1.B,t11);
    h[6|d] = lc(n1.D,t00, n1.E,t11);
    h[2|d] = cmul(p,   h[2|d]);
    h[4|d] = cmul(pcj, h[4|d]);
  }
  #pragma unroll
  for (int i=0;i<8;i++){
    int a=(i>>2)&1, cc=(i>>1)&1, d=i&1;
    slab[bp ^ (a?KA:0) ^ (bsel?KB:0) ^ (cc?KC:0) ^ (d?KD:0)] = h[i];
  }
}

// ---------------- reduced T(5,0): 1q map on q5 (col bit 0, row bit 6) ----------------
__device__ __forceinline__ void redT50(cplx* __restrict__ slab, float4 rc, float g6,
                                       N1C n1, N1C n2, int t){
  constexpr int KR = KPc(6), KCb = 1;
  #pragma unroll
  for (int grp=0; grp<2; grp++){
    int bp = base_s(t | (grp<<9));
    cplx v00 = slab[bp], v01 = slab[bp^KCb], v10 = slab[bp^KR], v11 = slab[bp^KR^KCb];
    v01 = sc(g6, v01); v10 = sc(g6, v10);                      // dephase by traced q6
    { cplx t00=v00, t11=v11;
      v00 = lc(n2.A,t00, n2.B,t11); v11 = lc(n2.D,t00, n2.E,t11);
      v01 = sc(n2.C,v01); v10 = sc(n2.C,v10); }
    float cy=rc.x, sy=rc.y;
    rot_pair(v00,v01,cy,sy); rot_pair(v10,v11,cy,sy);
    rot_pair(v00,v10,cy,sy); rot_pair(v01,v11,cy,sy);
    { cplx t00=v00, t11=v11;
      v00 = lc(n1.A,t00, n1.B,t11); v11 = lc(n1.D,t00, n1.E,t11);
      v01 = cmul(make_float2(rc.z,rc.w),  v01);
      v10 = cmul(make_float2(rc.z,-rc.w), v10); }
    slab[bp] = v00; slab[bp^KCb] = v01; slab[bp^KR] = v10; slab[bp^KR^KCb] = v11;
  }
}

// ---------------- backward 4-way adjoint stage (r11 algebra, 10-bit masks) ----------------
template<int V>
__device__ __forceinline__ void astage_q4b(cplx* __restrict__ slab, float4 rc, int bp,
                                           int bsel, int dsel, N1C n1a, N1C n2a,
                                           float alpha, float beta){
  constexpr int KA=maskB(5+V), KB=maskB(4+V), KC=1<<V, KD=1<<(V-1);
  int fix = (bsel?KB:0) ^ (dsel?KD:0);
  cplx v[4];
  v[0] = slab[bp ^ fix];
  v[1] = slab[bp ^ fix ^ KC];
  v[2] = slab[bp ^ fix ^ KA];
  v[3] = slab[bp ^ fix ^ KA ^ KC];
  cplx p  = make_float2(rc.z, -rc.w);
  cplx pc = make_float2(rc.z,  rc.w);
  float cy=rc.x, sy=-rc.y;
  {
    cplx t00=v[0], t11=v[3];
    v[0]=lc(n1a.A,t00, n1a.B,t11);
    v[3]=lc(n1a.D,t00, n1a.E,t11);
    v[1]=cmul(p,v[1]); v[2]=cmul(pc,v[2]);
    rot_pair(v[0],v[1],cy,sy); rot_pair(v[2],v[3],cy,sy);
    rot_pair(v[0],v[2],cy,sy); rot_pair(v[1],v[3],cy,sy);
  }
  #pragma unroll
  for (int j=0;j<4;j++){
    float rx = __shfl_xor(v[j].x, 3, 64);
    float ry = __shfl_xor(v[j].y, 3, 64);
    v[j] = make_float2(alpha*v[j].x + beta*rx, alpha*v[j].y + beta*ry);
  }
  {
    cplx t00=v[0], t11=v[3];
    v[0]=lc(n2a.A,t00, n2a.B,t11);
    v[3]=lc(n2a.D,t00, n2a.E,t11);
    v[1]=sc(n2a.C,v[1]); v[2]=sc(n2a.C,v[2]);
  }
  int sb = bsel ? KB : 0;
  slab[bp ^ sb            ^ (dsel?KD:0)]      = v[0];
  slab[bp ^ sb ^ KC       ^ (dsel?0:KD)]      = v[1];
  slab[bp ^ (sb^KB) ^ KA  ^ (dsel?KD:0)]      = v[2];
  slab[bp ^ (sb^KB) ^ KA ^ KC ^ (dsel?0:KD)]  = v[3];
}

#define SLOT2(UU, FI, VV, BI) { \
  if (t < 512) fstage2<UU>(fslab, sS[FI], baseF<UU>(gf), bf, n1, n2, a0,b0,a1,b1); \
  else if (t < 768) astage_q4b<VV>(bslab, sS[BI], baseBk<VV>(gb), bb_, db_, n1a, n2a, alpha, beta); \
  __syncthreads(); }

// ---------------- one kernel: 32 blocks, one per sample ----------------
__global__ __launch_bounds__(1024) void fused_kernel(const float* __restrict__ x,
                                                     const float* __restrict__ w,
                                                     float* __restrict__ out){
  __shared__ cplx fslab[4096];      // 32 KB forward 6-qubit state
  __shared__ cplx bslab[1024];      // 8 KB backward 5-qubit operator
  __shared__ float4 sS[48];
  __shared__ float sm[28];
  __shared__ float red[16];
  int t = threadIdx.x, s = blockIdx.x;
  N1C n1 = noise_coeffs(0.0003f);
  N1C n2 = noise_coeffs(0.0065f);
  N1C n1a = mkadj(n1), n2a = mkadj(n2);
  // forward split ids
  int bf = t & 1, gf = t >> 1;
  float a0 = bf ? n2.C : n2.A;
  float b0 = bf ? 0.f  : n2.B;
  float a1 = bf ? n2.E : n2.C;
  float b1 = bf ? n2.D : 0.f;
  // backward split ids (threads 512-767)
  int db_ = t & 1, bb_ = (t >> 1) & 1, gb = (t >> 2) & 63;
  float alpha = (bb_==db_) ? (bb_ ? n2a.E : n2a.A) : n2a.C;
  float beta  = (bb_==db_) ? (bb_ ? n2a.D : n2a.B) : 0.f;

  if (t < 48){
    float w0=w[t*2], w1=w[t*2+1];
    sS[t] = make_float4(cosf(0.5f*w0), sinf(0.5f*w0), n1.C*cosf(w1), -n1.C*sinf(w1));
  }
  if (t < 7){
    float xv = x[s*8+t];
    float c = cosf(0.5f*xv), sn = sinf(0.5f*xv);
    float p00=c*c, p01=c*sn, p11=sn*sn;
    sm[t*4+0]=n1.A*p00+n1.B*p11; sm[t*4+1]=n1.C*p01;
    sm[t*4+2]=n1.C*p01;          sm[t*4+3]=n1.D*p00+n1.E*p11;
  }
  __syncthreads();
  // forward init: 6-qubit product state (q6,q7 handled via γ6 / drop)
  #pragma unroll
  for (int k=0;k<4;k++){
    int L = k*1024 + t, rl = L>>6, cl = L&63;
    float v = 1.f;
    #pragma unroll
    for (int q=0;q<6;q++)
      v *= sm[q*4 + ((rl>>(5-q))&1)*2 + ((cl>>(5-q))&1)];
    fslab[physof(L)] = make_float2(v, 0.f);
  }
  // backward init: Z0 ⊗ I on 5-qubit space (q0 = bit 4)
  if (t >= 512 && t < 768){
    int local = t - 512;
    #pragma unroll
    for (int k=0;k<4;k++){
      int o = k*256 + local, r = o>>5, c = o&31;
      bslab[physB(o)] = make_float2((r==c) ? ((r&16)? -1.f : 1.f) : 0.f, 0.f);
    }
  }
  float g6 = 2.f * sm[25];          // n1.C * sin(x6)
  __syncthreads();

  // 11 slots: fwd {T(0..4,0), redT50, T(0..4,1)} ∥ bwd {10 adjoint stages, layers 5..2}
  SLOT2(5, 0, 4, 40)    // T(0,0) | T+(0,5)
  SLOT2(4, 1, 3, 33)    // T(1,0) | T+(1,4)
  SLOT2(3, 2, 4, 32)    // T(2,0) | T+(0,4)
  SLOT2(2, 3, 2, 26)    // T(3,0) | T+(2,3)
  SLOT2(1, 4, 3, 25)    // T(4,0) | T+(1,3)
  {
    if (t < 512) redT50(fslab, sS[5], g6, n1, n2, t);
    else if (t < 768) astage_q4b<4>(bslab, sS[24], baseBk<4>(gb), bb_, db_, n1a, n2a, alpha, beta);
    __syncthreads();
  }
  SLOT2(5, 8, 1, 19)    // T(0,1) | T+(3,2)
  SLOT2(4, 9, 2, 18)    // T(1,1) | T+(2,2)
  SLOT2(3,10, 3, 17)    // T(2,1) | T+(1,2)
  SLOT2(2,11, 4, 16)    // T(3,1) | T+(0,2)
  {
    if (t < 512) fstage2<1>(fslab, sS[12], baseF<1>(gf), bf, n1, n2, a0,b0,a1,b1);
    __syncthreads();
  }

  // contraction: E = Σ_{r,c} O[r,c] · Σ_{b5} ρ[(c|b5),(r|b5)]  (q5 traced with identity)
  float acc;
  {
    int r04 = t >> 5, c04 = t & 31;
    cplx Ov = bslab[physB(t)];
    cplx z = make_float2(0.f,0.f);
    #pragma unroll
    for (int b5=0;b5<2;b5++){
      int L = ((((c04<<1)|b5)<<6) | ((r04<<1)|b5));
      cplx rv = fslab[physof(L)];
      z = make_float2(z.x+rv.x, z.y+rv.y);
    }
    acc = Ov.x*z.x - Ov.y*z.y;
  }
  #pragma unroll
  for (int off=32; off>0; off>>=1) acc += __shfl_down(acc, off, 64);
  if ((t&63)==0) red[t>>6] = acc;
  __syncthreads();
  if (t==0){
    float v = 0.f;
    #pragma unroll
    for (int k=0;k<16;k++) v += red[k];
    out[s] = v;
  }
}

extern "C" void kernel_launch(void* const* d_in, const int* in_sizes, int n_in,
                              void* d_out, int out_size, void* d_ws, size_t ws_size,
                              hipStream_t stream) {
  const float* x = (const float*)d_in[0];   // [32,8]
  const float* w = (const float*)d_in[1];   // [6,8,2]
  float* out = (float*)d_out;               // [32,1] f32

  fused_kernel<<<BATCH, 1024, 0, stream>>>(x, w, out);
}

// Round 18
// 20.113 us; speedup vs baseline: 2.6264x; 1.1128x over previous
//
#include <hip/hip_runtime.h>
#include <cmath>

// Noisy 8-qubit density-matrix sim, batch 32, depth 6 — dual-chain split, DPP + T41-fold.
// E_b = Tr[(Λ25†(Z0) ⊗ I) · Λ01(ρ_b)]:
//   backward (threads 512-767): adjoint layers 5..2 lightcone = 10 stages, support {0..4}.
//   forward (threads 0-511): layers 0..1 reduced = 10 stages on 6-qubit slab:
//     T(0..4,0), redT(5,0), T(0..3,1).  T(4,1) FOLDED into the contraction via the
//     precomputed 4x4 complex table C4 = S4dense∘N2sup over CNOT-twisted q4q5-traced
//     combos Q[α,γ] (exact: N2(q5) disappears under trace since A+D=B+E=1).
//   Cross-partner exchanges via DPP quad_perm (VALU pipe), not shfl (LDS pipe):
//     lane^1 = 0xB1, lane^3 = 0x1B.
// 10 slots, wave-specialized concurrency, contraction fused in-block. 32 blocks, 1 launch.

typedef float2 cplx;
#define BATCH 32

__device__ __forceinline__ cplx cmul(cplx a, cplx b){
  return make_float2(a.x*b.x - a.y*b.y, a.x*b.y + a.y*b.x);
}
__device__ __forceinline__ cplx cadd(cplx a, cplx b){ return make_float2(a.x+b.x, a.y+b.y); }
__device__ __forceinline__ cplx lc(float a, cplx u, float b, cplx v){
  return make_float2(a*u.x + b*v.x, a*u.y + b*v.y);
}
__device__ __forceinline__ cplx sc(float a, cplx u){ return make_float2(a*u.x, a*u.y); }

struct N1C { float A,B,C,D,E; };
__device__ __forceinline__ N1C noise_coeffs(float g){
  float ga = g*0.3f, gp = g*0.2f, p = g*0.5f;
  N1C n;
  n.A = 1.0f - 2.0f*p/3.0f;
  n.D = 2.0f*p/3.0f;
  n.B = ga*n.A + n.D*(1.0f-ga);
  n.E = n.D*ga + n.A*(1.0f-ga);
  n.C = (1.0f - 4.0f*p/3.0f) * sqrtf(1.0f-ga) * sqrtf(1.0f-gp);
  return n;
}
__device__ __forceinline__ N1C mkadj(N1C n){
  N1C a; a.A=n.A; a.B=n.D; a.C=n.C; a.D=n.B; a.E=n.E; return a;
}

// DPP quad-perm exchanges (VALU pipe): partner = lane^1 / lane^3
__device__ __forceinline__ float dpp_x1(float v){
  return __int_as_float(__builtin_amdgcn_mov_dpp(__float_as_int(v), 0xB1, 0xF, 0xF, true));
}
__device__ __forceinline__ float dpp_x3(float v){
  return __int_as_float(__builtin_amdgcn_mov_dpp(__float_as_int(v), 0x1B, 0xF, 0xF, true));
}

// ---- forward 12-bit slab: qubit q: col bit 5-q, row bit 11-q; phys = L ^ rot3(rl) ----
__device__ __forceinline__ int physof(int L){
  int rl = L >> 6;
  int rot = ((rl<<3)|(rl>>3)) & 63;
  return L ^ rot;
}
__device__ __forceinline__ constexpr int KPc(int p){
  return (p < 6) ? (1<<p) : ((1<<p) | (1 << ((p-3)%6)));
}
// ---- backward 10-bit slab: qubit q: col bit 4-q, row bit 9-q; phys = L ^ rot2(rl) ----
__device__ __forceinline__ int physB(int L){
  int rl = L >> 5;
  int rot = ((rl<<2)|(rl>>3)) & 31;
  return L ^ rot;
}
__device__ __forceinline__ constexpr int maskB(int p){
  return (p < 5) ? (1<<p) : ((1<<p) | (1 << ((p-3)%5)));
}

// forward 2-way tables (r17 verbatim)
template<int U>
__device__ __forceinline__ int baseF(int g){
  constexpr int F[6][8] = {
    {0,0,0,0,0,0,0,0},
    {2,4,9, 3,5,8,10,11},   // U=1
    {0,3,5, 4,6,9,10,11},   // U=2
    {0,1,4, 5,6,7,10,11},   // U=3
    {1,2,5, 0,6,7,8,11},    // U=4
    {0,2,3, 1,6,7,8,9}};    // U=5
  int b = 0;
  #pragma unroll
  for (int i=0;i<8;i++) b ^= (-((g>>i)&1)) & KPc(F[U][i]);
  return b;
}
// backward 4-way tables (r17 verbatim)
template<int V>
__device__ __forceinline__ int baseBk(int g){
  constexpr int F[5][6] = {
    {0,0,0,0,0,0},
    {3,4, 2,7,8,9},   // V=1
    {0,4, 3,5,8,9},   // V=2
    {0,1, 4,5,6,9},   // V=3
    {1,2, 0,5,6,7}};  // V=4
  int b = 0;
  #pragma unroll
  for (int i=0;i<6;i++) b ^= (-((g>>i)&1)) & maskB(F[V][i]);
  return b;
}
__device__ __forceinline__ int base_s(int t){
  constexpr int P[10] = {1,2,3,9, 4,5,7,8,10,11};
  int b = 0;
  #pragma unroll
  for (int i=0;i<10;i++) b ^= (-((t>>i)&1)) & KPc(P[i]);
  return b;
}

__device__ __forceinline__ void rot_pair(cplx& v0, cplx& v1, float cy, float sy){
  cplx a=v0, b=v1;
  v0 = make_float2(cy*a.x - sy*b.x, cy*a.y - sy*b.y);
  v1 = make_float2(sy*a.x + cy*b.x, sy*a.y + cy*b.y);
}

// ---------------- forward 2-way stage (r17, DPP cross) ----------------
template<int U>
__device__ __forceinline__ void fstage2(cplx* __restrict__ slab, float4 rc, int bp, int bsel,
                                        N1C n1, N1C n2, float a0, float b0, float a1, float b1){
  constexpr int KA=KPc(6+U), KB=KPc(5+U), KC=1<<U, KD=1<<(U-1);
  cplx h[8];
  #pragma unroll
  for (int i=0;i<8;i++){
    int a=(i>>2)&1, cc=(i>>1)&1, d=i&1;
    h[i] = slab[bp ^ (a?KA:0) ^ ((bsel^a)?KB:0) ^ (cc?KC:0) ^ ((d^cc)?KD:0)];
  }
  #pragma unroll
  for (int d=0;d<2;d++){
    cplx t00=h[d], t11=h[6|d];
    h[d]   = lc(n2.A,t00, n2.B,t11);
    h[6|d] = lc(n2.D,t00, n2.E,t11);
    h[2|d] = sc(n2.C, h[2|d]);
    h[4|d] = sc(n2.C, h[4|d]);
  }
  #pragma unroll
  for (int j=0;j<4;j++){
    int i0 = j<<1;
    float r0x = dpp_x1(h[i0].x),   r0y = dpp_x1(h[i0].y);
    float r1x = dpp_x1(h[i0|1].x), r1y = dpp_x1(h[i0|1].y);
    cplx h0 = h[i0], h1 = h[i0|1];
    h[i0]   = make_float2(a0*h0.x + b0*r1x, a0*h0.y + b0*r1y);
    h[i0|1] = make_float2(a1*h1.x + b1*r0x, a1*h1.y + b1*r0y);
  }
  float cy=rc.x, sy=rc.y;
  #pragma unroll
  for (int a=0;a<2;a++)
    #pragma unroll
    for (int d=0;d<2;d++) rot_pair(h[(a<<2)|d], h[(a<<2)|2|d], cy, sy);
  #pragma unroll
  for (int cc=0;cc<2;cc++)
    #pragma unroll
    for (int d=0;d<2;d++) rot_pair(h[(cc<<1)|d], h[4|(cc<<1)|d], cy, sy);
  cplx p = make_float2(rc.z, rc.w), pcj = make_float2(rc.z, -rc.w);
  #pragma unroll
  for (int d=0;d<2;d++){
    cplx t00=h[d], t11=h[6|d];
    h[d]   = lc(n1.A,t00, n1.B,t11);
    h[6|d] = lc(n1.D,t00, n1.E,t11);
    h[2|d] = cmul(p,   h[2|d]);
    h[4|d] = cmul(pcj, h[4|d]);
  }
  #pragma unroll
  for (int i=0;i<8;i++){
    int a=(i>>2)&1, cc=(i>>1)&1, d=i&1;
    slab[bp ^ (a?KA:0) ^ (bsel?KB:0) ^ (cc?KC:0) ^ (d?KD:0)] = h[i];
  }
}

// ---------------- reduced T(5,0) (r17 verbatim) ----------------
__device__ __forceinline__ void redT50(cplx* __restrict__ slab, float4 rc, float g6,
                                       N1C n1, N1C n2, int t){
  constexpr int KR = KPc(6), KCb = 1;
  #pragma unroll
  for (int grp=0; grp<2; grp++){
    int bp = base_s(t | (grp<<9));
    cplx v00 = slab[bp], v01 = slab[bp^KCb], v10 = slab[bp^KR], v11 = slab[bp^KR^KCb];
    v01 = sc(g6, v01); v10 = sc(g6, v10);
    { cplx t00=v00, t11=v11;
      v00 = lc(n2.A,t00, n2.B,t11); v11 = lc(n2.D,t00, n2.E,t11);
      v01 = sc(n2.C,v01); v10 = sc(n2.C,v10); }
    float cy=rc.x, sy=rc.y;
    rot_pair(v00,v01,cy,sy); rot_pair(v10,v11,cy,sy);
    rot_pair(v00,v10,cy,sy); rot_pair(v01,v11,cy,sy);
    { cplx t00=v00, t11=v11;
      v00 = lc(n1.A,t00, n1.B,t11); v11 = lc(n1.D,t00, n1.E,t11);
      v01 = cmul(make_float2(rc.z,rc.w),  v01);
      v10 = cmul(make_float2(rc.z,-rc.w), v10); }
    slab[bp] = v00; slab[bp^KCb] = v01; slab[bp^KR] = v10; slab[bp^KR^KCb] = v11;
  }
}

// ---------------- backward 4-way adjoint stage (r17, DPP cross) ----------------
template<int V>
__device__ __forceinline__ void astage_q4b(cplx* __restrict__ slab, float4 rc, int bp,
                                           int bsel, int dsel, N1C n1a, N1C n2a,
                                           float alpha, float beta){
  constexpr int KA=maskB(5+V), KB=maskB(4+V), KC=1<<V, KD=1<<(V-1);
  int fix = (bsel?KB:0) ^ (dsel?KD:0);
  cplx v[4];
  v[0] = slab[bp ^ fix];
  v[1] = slab[bp ^ fix ^ KC];
  v[2] = slab[bp ^ fix ^ KA];
  v[3] = slab[bp ^ fix ^ KA ^ KC];
  cplx p  = make_float2(rc.z, -rc.w);
  cplx pc = make_float2(rc.z,  rc.w);
  float cy=rc.x, sy=-rc.y;
  {
    cplx t00=v[0], t11=v[3];
    v[0]=lc(n1a.A,t00, n1a.B,t11);
    v[3]=lc(n1a.D,t00, n1a.E,t11);
    v[1]=cmul(p,v[1]); v[2]=cmul(pc,v[2]);
    rot_pair(v[0],v[1],cy,sy); rot_pair(v[2],v[3],cy,sy);
    rot_pair(v[0],v[2],cy,sy); rot_pair(v[1],v[3],cy,sy);
  }
  #pragma unroll
  for (int j=0;j<4;j++){
    float rx = dpp_x3(v[j].x);
    float ry = dpp_x3(v[j].y);
    v[j] = make_float2(alpha*v[j].x + beta*rx, alpha*v[j].y + beta*ry);
  }
  {
    cplx t00=v[0], t11=v[3];
    v[0]=lc(n2a.A,t00, n2a.B,t11);
    v[3]=lc(n2a.D,t00, n2a.E,t11);
    v[1]=sc(n2a.C,v[1]); v[2]=sc(n2a.C,v[2]);
  }
  int sb = bsel ? KB : 0;
  slab[bp ^ sb            ^ (dsel?KD:0)]      = v[0];
  slab[bp ^ sb ^ KC       ^ (dsel?0:KD)]      = v[1];
  slab[bp ^ (sb^KB) ^ KA  ^ (dsel?KD:0)]      = v[2];
  slab[bp ^ (sb^KB) ^ KA ^ KC ^ (dsel?0:KD)]  = v[3];
}

#define SLOT2(UU, FI, VV, BI) { \
  if (t < 512) fstage2<UU>(fslab, sS[FI], baseF<UU>(gf), bf, n1, n2, a0,b0,a1,b1); \
  else if (t < 768) astage_q4b<VV>(bslab, sS[BI], baseBk<VV>(gb), bb_, db_, n1a, n2a, alpha, beta); \
  __syncthreads(); }

// ---------------- one kernel: 32 blocks, one per sample ----------------
__global__ __launch_bounds__(1024) void fused_kernel(const float* __restrict__ x,
                                                     const float* __restrict__ w,
                                                     float* __restrict__ out){
  __shared__ cplx fslab[4096];      // 32 KB forward 6-qubit state
  __shared__ cplx bslab[1024];      // 8 KB backward 5-qubit operator
  __shared__ float4 sS[48];
  __shared__ float sm[28];
  __shared__ cplx C4s[16];          // folded-T(4,1) contraction table
  __shared__ float red[16];
  int t = threadIdx.x, s = blockIdx.x;
  N1C n1 = noise_coeffs(0.0003f);
  N1C n2 = noise_coeffs(0.0065f);
  N1C n1a = mkadj(n1), n2a = mkadj(n2);
  int bf = t & 1, gf = t >> 1;
  float a0 = bf ? n2.C : n2.A;
  float b0 = bf ? 0.f  : n2.B;
  float a1 = bf ? n2.E : n2.C;
  float b1 = bf ? n2.D : 0.f;
  int db_ = t & 1, bb_ = (t >> 1) & 1, gb = (t >> 2) & 63;
  float alpha = (bb_==db_) ? (bb_ ? n2a.E : n2a.A) : n2a.C;
  float beta  = (bb_==db_) ? (bb_ ? n2a.D : n2a.B) : 0.f;

  if (t < 48){
    float w0=w[t*2], w1=w[t*2+1];
    sS[t] = make_float4(cosf(0.5f*w0), sinf(0.5f*w0), n1.C*cosf(w1), -n1.C*sinf(w1));
  }
  if (t < 7){
    float xv = x[s*8+t];
    float c = cosf(0.5f*xv), sn = sinf(0.5f*xv);
    float p00=c*c, p01=c*sn, p11=sn*sn;
    sm[t*4+0]=n1.A*p00+n1.B*p11; sm[t*4+1]=n1.C*p01;
    sm[t*4+2]=n1.C*p01;          sm[t*4+3]=n1.D*p00+n1.E*p11;
  }
  if (t == 63){
    // C4 = S4dense(l=1,q=4) ∘ N2sup  (T(4,1) fold; q5 noise vanishes under trace)
    float w0=w[24], w1=w[25];
    float c = cosf(0.5f*w0), sn = sinf(0.5f*w0);
    float U[2][2] = {{c,-sn},{sn,c}};
    cplx ph01 = make_float2(cosf(w1), -sinf(w1));
    cplx ph10 = make_float2(ph01.x, -ph01.y);
    cplx S4[16];
    #pragma unroll
    for (int a=0;a<2;a++)
      #pragma unroll
      for (int b=0;b<2;b++){
        int k = 2*a+b;
        float u0a=U[0][a], u0b=U[0][b], u1a=U[1][a], u1b=U[1][b];
        S4[0*4+k] = make_float2(n1.A*u0a*u0b + n1.B*u1a*u1b, 0.f);
        S4[1*4+k] = sc(n1.C*u0a*u1b, ph01);
        S4[2*4+k] = sc(n1.C*u1a*u0b, ph10);
        S4[3*4+k] = make_float2(n1.D*u0a*u0b + n1.E*u1a*u1b, 0.f);
      }
    #pragma unroll
    for (int j=0;j<4;j++){
      C4s[j*4+0] = cadd(sc(n2.A, S4[j*4+0]), sc(n2.D, S4[j*4+3]));
      C4s[j*4+1] = sc(n2.C, S4[j*4+1]);
      C4s[j*4+2] = sc(n2.C, S4[j*4+2]);
      C4s[j*4+3] = cadd(sc(n2.B, S4[j*4+0]), sc(n2.E, S4[j*4+3]));
    }
  }
  __syncthreads();
  // forward init: 6-qubit product state
  #pragma unroll
  for (int k=0;k<4;k++){
    int L = k*1024 + t, rl = L>>6, cl = L&63;
    float v = 1.f;
    #pragma unroll
    for (int q=0;q<6;q++)
      v *= sm[q*4 + ((rl>>(5-q))&1)*2 + ((cl>>(5-q))&1)];
    fslab[physof(L)] = make_float2(v, 0.f);
  }
  // backward init: Z0 ⊗ I on 5-qubit space
  if (t >= 512 && t < 768){
    int local = t - 512;
    #pragma unroll
    for (int k=0;k<4;k++){
      int o = k*256 + local, r = o>>5, c = o&31;
      bslab[physB(o)] = make_float2((r==c) ? ((r&16)? -1.f : 1.f) : 0.f, 0.f);
    }
  }
  float g6 = 2.f * sm[25];          // n1.C * sin(x6)
  __syncthreads();

  // 10 slots: fwd {T(0..4,0), redT50, T(0..3,1)} ∥ bwd {10 adjoint stages}
  SLOT2(5, 0, 4, 40)    // T(0,0) | T+(0,5)
  SLOT2(4, 1, 3, 33)    // T(1,0) | T+(1,4)
  SLOT2(3, 2, 4, 32)    // T(2,0) | T+(0,4)
  SLOT2(2, 3, 2, 26)    // T(3,0) | T+(2,3)
  SLOT2(1, 4, 3, 25)    // T(4,0) | T+(1,3)
  {
    if (t < 512) redT50(fslab, sS[5], g6, n1, n2, t);
    else if (t < 768) astage_q4b<4>(bslab, sS[24], baseBk<4>(gb), bb_, db_, n1a, n2a, alpha, beta);
    __syncthreads();
  }
  SLOT2(5, 8, 1, 19)    // T(0,1) | T+(3,2)
  SLOT2(4, 9, 2, 18)    // T(1,1) | T+(2,2)
  SLOT2(3,10, 3, 17)    // T(2,1) | T+(1,2)
  SLOT2(2,11, 4, 16)    // T(3,1) | T+(0,2)

  // contraction with T(4,1) folded:
  // E = Σ O[r04,c04] Σ_{α,γ} C4[(c4<<1)|r4][2α+γ] · Q[α,γ]
  // Q[α,γ] = Σ_b ρ[row=(c03,α,b⊕α), col=(r03,γ,b⊕γ)]
  float acc;
  {
    int r04 = t >> 5, c04 = t & 31;
    int r03 = r04 >> 1, r4 = r04 & 1, c03 = c04 >> 1, c4 = c04 & 1;
    int rbase = c03 << 2, cbase = r03 << 2;
    #define FEL(al,be,ga,de) fslab[physof((((rbase|((al)<<1)|(be))<<6) | (cbase|((ga)<<1)|(de))))]
    cplx Q0 = cadd(FEL(0,0,0,0), FEL(0,1,0,1));
    cplx Q1 = cadd(FEL(0,0,1,1), FEL(0,1,1,0));
    cplx Q2 = cadd(FEL(1,1,0,0), FEL(1,0,0,1));
    cplx Q3 = cadd(FEL(1,1,1,1), FEL(1,0,1,0));
    #undef FEL
    int j = ((c4<<1)|r4) << 2;
    cplx z = cmul(C4s[j], Q0);
    z = cadd(z, cmul(C4s[j|1], Q1));
    z = cadd(z, cmul(C4s[j|2], Q2));
    z = cadd(z, cmul(C4s[j|3], Q3));
    cplx Ov = bslab[physB(t)];
    acc = Ov.x*z.x - Ov.y*z.y;
  }
  #pragma unroll
  for (int off=32; off>0; off>>=1) acc += __shfl_down(acc, off, 64);
  if ((t&63)==0) red[t>>6] = acc;
  __syncthreads();
  if (t==0){
    float v = 0.f;
    #pragma unroll
    for (int k=0;k<16;k++) v += red[k];
    out[s] = v;
  }
}

extern "C" void kernel_launch(void* const* d_in, const int* in_sizes, int n_in,
                              void* d_out, int out_size, void* d_ws, size_t ws_size,
                              hipStream_t stream) {
  const float* x = (const float*)d_in[0];   // [32,8]
  const float* w = (const float*)d_in[1];   // [6,8,2]
  float* out = (float*)d_out;               // [32,1] f32

  fused_kernel<<<BATCH, 1024, 0, stream>>>(x, w, out);
}